// Round 5
// baseline (427.005 us; speedup 1.0000x reference)
//
#include <hip/hip_runtime.h>

// ---------------- constants ----------------
#define NROWS 16384
#define NF 39
#define NV 100000
#define NE 16
#define HID 400
#define K1 624     // real K of layer 1 (39*16)
#define K1T 640    // padded K span for layer 1 (h0 zero-padded to this)
#define K2T 448    // padded K span for layers 2/3 (real 400)
#define BN_EPS 1e-5f

typedef short short8v __attribute__((ext_vector_type(8)));
typedef float float4v __attribute__((ext_vector_type(4)));

__device__ __forceinline__ float bf2f(unsigned short u) {
    unsigned int x = ((unsigned int)u) << 16;
    return __uint_as_float(x);
}
__device__ __forceinline__ unsigned short f2bf(float f) {
    unsigned int x = __float_as_uint(f);
    unsigned int r = (x + 0x7FFFu + ((x >> 16) & 1u)) >> 16;
    return (unsigned short)r;
}

// async global->LDS DMA, 16B per lane. LDS dest is wave-uniform base + lane*16.
__device__ __forceinline__ void gload16(const unsigned short* g, unsigned short* l) {
    __builtin_amdgcn_global_load_lds(
        (const __attribute__((address_space(1))) unsigned int*)g,
        (__attribute__((address_space(3))) unsigned int*)l,
        16, 0, 0);
}

// Counted-wait barriers. Raw s_barrier does NOT auto-drain counters, so the 5
// next-tile loads stay in flight across the MFMA phase.
__device__ __forceinline__ void bar_vm5() {
    asm volatile("s_waitcnt vmcnt(5) lgkmcnt(0)" ::: "memory");
    __builtin_amdgcn_s_barrier();
    __builtin_amdgcn_sched_barrier(0);
}
__device__ __forceinline__ void bar_vm0() {
    asm volatile("s_waitcnt vmcnt(0) lgkmcnt(0)" ::: "memory");
    __builtin_amdgcn_s_barrier();
    __builtin_amdgcn_sched_barrier(0);
}
__device__ __forceinline__ void bar_lgkm() {
    asm volatile("s_waitcnt lgkmcnt(0)" ::: "memory");
    __builtin_amdgcn_s_barrier();
    __builtin_amdgcn_sched_barrier(0);
}

// ---------------- prep: embed (blocks 0..4095) + weight-convert + zero sums -------------
#define EMB_BLOCKS 4096
#define W1E (448 * 640)           // 286720
#define W2E (448 * 448)           // 200704
#define TCVT (W1E + 2 * W2E)      // 688128 elems
#define CVT_BLOCKS (TCVT / 8 / 256)   // 336

__global__ __launch_bounds__(256) void prep_kernel(const int* __restrict__ Xi,
                                                   const float* __restrict__ Xv,
                                                   const float* __restrict__ emb1,
                                                   const float* __restrict__ emb2,
                                                   const float* __restrict__ W1,
                                                   const float* __restrict__ W2,
                                                   const float* __restrict__ W3,
                                                   unsigned short* __restrict__ h0,
                                                   float* __restrict__ f12,
                                                   unsigned short* __restrict__ w1b,
                                                   unsigned short* __restrict__ w2b,
                                                   unsigned short* __restrict__ w3b,
                                                   float* __restrict__ sums) {
    int b = blockIdx.x;
    int tid = threadIdx.x;
    if (b < EMB_BLOCKS) {
        int wave = tid >> 6, lane = tid & 63;
        int n = b * 4 + wave;
        __shared__ int sidx[4][NF + 1];
        __shared__ float sxv[4][NF + 1];
        __shared__ __align__(16) float sx[4][NF * NE];
        __shared__ float srn[4][NE];
        // Load Xi/Xv to regs, publish to LDS, and ISSUE the emb1 gather immediately.
        int myidx = 0; float myxv = 0.f, e1v = 0.f;
        if (lane < NF) {
            myidx = Xi[n * NF + lane];
            myxv = Xv[n * NF + lane];
            sidx[wave][lane] = myidx;
            sxv[wave][lane] = myxv;
            e1v = emb1[(size_t)lane * NV + (size_t)myidx];   // long-latency, in flight
        }
        __syncthreads();
        const float4* e2 = (const float4*)emb2;
        // prefetch all (<=3) emb2 gathers to regs before any LDS store -> full MLP
        float4 vv[3];
        float mm[3];
        int ii[3];
        #pragma unroll
        for (int t = 0; t < 3; ++t) {
            int i = lane + 64 * t;
            ii[t] = i;
            if (i < NF * 4) {
                int f = i >> 2, q = i & 3;
                vv[t] = e2[((size_t)f * NV + (size_t)sidx[wave][f]) * 4 + q];
                mm[t] = sxv[wave][f];
            }
        }
        #pragma unroll
        for (int t = 0; t < 3; ++t) {
            int i = ii[t];
            if (i < NF * 4) {
                int f = i >> 2, q = i & 3;
                float4 v = vv[t];
                float m = mm[t];
                float4 o; o.x = v.x * m; o.y = v.y * m; o.z = v.z * m; o.w = v.w * m;
                *(float4*)&sx[wave][f * NE + q * 4] = o;
            }
        }
        __syncthreads();
        float f2 = 0.f;
        if (lane < NE) {
            float ss = 0.f, sm = 0.f;
            #pragma unroll
            for (int f = 0; f < NF; ++f) {
                float v = sx[wave][f * NE + lane];
                ss += v * v;
                sm += v;
            }
            float rn = 1.f / fmaxf(sqrtf(ss), 1e-12f);
            srn[wave][lane] = rn;
            float s = sm * rn;
            f2 = 0.5f * (s * s - ss * rn * rn);
        }
        float f1 = (lane < NF) ? e1v * myxv : 0.f;
        float tot = f1 + f2;
        #pragma unroll
        for (int o = 32; o; o >>= 1) tot += __shfl_down(tot, o, 64);
        if (lane == 0) f12[n] = tot;
        __syncthreads();
        // h0 store: 80 vec8 chunks per row (zero-padded to K1T=640).
        for (int i = lane; i < 80; i += 64) {
            int k0 = i * 8;
            short8v o = (short8v){0, 0, 0, 0, 0, 0, 0, 0};
            if (i < 78) {
                #pragma unroll
                for (int e = 0; e < 8; ++e) {
                    int k = k0 + e;
                    o[e] = (short)f2bf(sx[wave][k] * srn[wave][k & 15]);
                }
            }
            *(short8v*)(h0 + (size_t)n * K1T + k0) = o;
        }
        return;
    }
    b -= EMB_BLOCKS;
    if (b < CVT_BLOCKS) {
        int gidx = b * 256 + tid;
        int e = gidx * 8;
        if (e < TCVT) {
            const float* W; unsigned short* O; int Kreal, Kt, base;
            if (e < W1E) { W = W1; O = w1b; Kreal = K1; Kt = K1T; base = 0; }
            else if (e < W1E + W2E) { W = W2; O = w2b; Kreal = HID; Kt = K2T; base = W1E; }
            else { W = W3; O = w3b; Kreal = HID; Kt = K2T; base = W1E + W2E; }
            int le = e - base;
            int r = le / Kt, k = le % Kt;
            short8v o;
            #pragma unroll
            for (int ee = 0; ee < 8; ++ee) {
                int kk = k + ee;
                o[ee] = (r < HID && kk < Kreal) ? (short)f2bf(W[(size_t)r * Kreal + kk]) : (short)0;
            }
            *(short8v*)(O + (size_t)r * Kt + k) = o;
        }
        return;
    }
    for (int i = tid; i < 2400; i += 256) sums[i] = 0.f;
}

// ---------------- bf16 MFMA GEMM: 512 thr, BM=64, BNT=224 -----------------------------
// v4 (occupancy): BM 128->64 halves the A-tile and the accumulator footprint.
// LDS ~79 KB -> 2 blocks/CU (16 waves/CU, was 8); grid (256,2)=512 blocks -> all CUs
// at 2 blocks each. Two independent blocks per CU overlap each other's barrier
// drains/prologue/epilogue — the latency the 1-block/CU schedule could never hide.
// Counted-vmcnt kept: 5 VMEM ops per wave per step (A:1, B:4 equalized) -> vmcnt(5).
// Per-wave tile: 16 rows x 112 cols, acc[1][7].
#define BM 64
#define BNT 224
#define BK 64

template <bool FUSE_BN>
__global__ __launch_bounds__(512, 4) void gemm_kernel(const unsigned short* __restrict__ A,
                                                      int lda, int Kreal, int Kt,
                                                      const unsigned short* __restrict__ W,  // 448 x Kt
                                                      const float* __restrict__ bias,
                                                      const float* __restrict__ psums,
                                                      const float* __restrict__ g,
                                                      const float* __restrict__ bt,
                                                      unsigned short* __restrict__ C,        // ldc = 400
                                                      float* __restrict__ sums) {
    __shared__ __align__(16) unsigned short As[2][BM * BK];    // 2 x 8 KB
    __shared__ __align__(16) unsigned short Bs[2][BNT * BK];   // 2 x 28 KB
    __shared__ float ssc[K2T], ssh[K2T];
    __shared__ float scol[BNT], qcol[BNT];
    int tid = threadIdx.x;
    int wave = tid >> 6, lane = tid & 63;
    int quad = lane >> 4, l16 = lane & 15;
    int mi = wave & 3, nj = wave >> 2;     // 4 row-groups x 16 rows; 2 col-groups x 112
    int m0 = blockIdx.x * BM;
    int n0 = blockIdx.y * BNT;
    int wbase = tid & ~63;   // wave*64

    if (FUSE_BN && tid < K2T) {
        float sc = 0.f, sh = 0.f;
        if (tid < HID) {
            const float invN = 1.f / (float)NROWS;
            float mu = psums[tid] * invN;
            float var = psums[HID + tid] * invN - mu * mu;
            float rstd = rsqrtf(var + BN_EPS);
            sc = g[tid] * rstd;
            sh = bt[tid] - mu * sc;
        }
        ssc[tid] = sc; ssh[tid] = sh;
    }
    if (tid < BNT) { scol[tid] = 0.f; qcol[tid] = 0.f; }

    const short8v zero8 = (short8v){0, 0, 0, 0, 0, 0, 0, 0};
    short8v Ar;

    // layer-1 A staging: async DMA, inverse-swizzled global source (1 load/thread:
    // 64 rows x 8 chunks = 512 = blockDim).
    auto stageA_g = [&](int buf, int kt) {
        int r = tid >> 3, c = tid & 7;
        int sc = c ^ (r & 7);
        gload16(A + (size_t)(m0 + r) * lda + kt + sc * 8,
                &As[buf][(size_t)wbase * 8]);
    };
    // B staging: async DMA; equalized to exactly 4 loads/thread (v>=1792 re-issues
    // the thread's i2=0 chunk: same source, same dest, identical bytes -> race-free).
    auto stageB = [&](int buf, int kt) {
        #pragma unroll
        for (int i2 = 0; i2 < 4; ++i2) {
            int v = tid + i2 * 512;
            int vv = (v < BNT * 8) ? v : tid;
            int dst = (v < BNT * 8) ? (i2 * 512 + wbase) : wbase;
            int r = vv >> 3, c = vv & 7;
            int sc = c ^ (r & 7);
            gload16(W + (size_t)(n0 + r) * Kt + kt + sc * 8,
                    &Bs[buf][(size_t)dst * 8]);
        }
    };
    // layers 2/3 A staging: reg load, BN+ReLU, swizzled ds_write (1 load/thread)
    auto loadA_regs = [&](int kt) {
        int r = tid >> 3, gc = tid & 7;
        int k = kt + gc * 8;
        Ar = (k < Kreal) ? *(const short8v*)(A + (size_t)(m0 + r) * lda + k) : zero8;
    };
    auto writeA_lds = [&](int buf, int kt) {
        int r = tid >> 3, gc = tid & 7;
        short8v val = Ar;
        #pragma unroll
        for (int e = 0; e < 8; ++e) {
            int k = kt + gc * 8 + e;
            float x = bf2f((unsigned short)val[e]);
            val[e] = (short)f2bf(fmaxf(x * ssc[k] + ssh[k], 0.f));
        }
        *(short8v*)(&As[buf][r * BK + ((gc ^ (r & 7)) * 8)]) = val;
    };

    float4v acc[7];
    #pragma unroll
    for (int f = 0; f < 7; ++f)
        acc[f] = (float4v){0.f, 0.f, 0.f, 0.f};

    // prologue: stage tile 0, full drain (once)
    if (FUSE_BN) loadA_regs(0); else stageA_g(0, 0);
    stageB(0, 0);
    __syncthreads();                       // ssc/ssh + scol ready; tile-0 DMA drained
    if (FUSE_BN) { writeA_lds(0, 0); __syncthreads(); }

    int nsteps = Kt / BK;
    int buf = 0;
    for (int s = 0; s < nsteps; ++s) {
        bool more = (s + 1 < nsteps);
        if (more) {
            if (FUSE_BN) loadA_regs((s + 1) * BK); else stageA_g(buf ^ 1, (s + 1) * BK);
            stageB(buf ^ 1, (s + 1) * BK);
        }
        if (more) bar_vm5(); else bar_vm0();   // barrier #1: buf staged & published
        __builtin_amdgcn_s_setprio(1);
        #pragma unroll
        for (int kk = 0; kk < BK; kk += 32) {
            int kc = kk >> 3;              // 0 or 4
            short8v af, bfr[7];
            {
                int r = mi * 16 + l16;
                af = *(const short8v*)(&As[buf][r * BK + (((quad + kc) ^ (r & 7)) * 8)]);
            }
            #pragma unroll
            for (int f = 0; f < 7; ++f) {
                int r = nj * 112 + f * 16 + l16;
                bfr[f] = *(const short8v*)(&Bs[buf][r * BK + (((quad + kc) ^ (r & 7)) * 8)]);
            }
            #pragma unroll
            for (int f = 0; f < 7; ++f)
                acc[f] = __builtin_amdgcn_mfma_f32_16x16x32_bf16(af, bfr[f], acc[f], 0, 0, 0);
        }
        __builtin_amdgcn_s_setprio(0);
        if (FUSE_BN && more) writeA_lds(buf ^ 1, (s + 1) * BK);  // hid under next wait
        bar_lgkm();                        // barrier #2: readers of buf done; ds_writes out
        buf ^= 1;
    }

    // epilogue: store C + per-column stats. C/D layout: col=lane&15, row=quad*4+reg
    #pragma unroll
    for (int f = 0; f < 7; ++f) {
        int lc = nj * 112 + f * 16 + l16;
        int col = n0 + lc;
        float bv = (col < HID) ? bias[col] : 0.f;
        float s = 0.f, q = 0.f;
        #pragma unroll
        for (int r = 0; r < 4; ++r) {
            int row = m0 + mi * 16 + quad * 4 + r;
            float v = acc[f][r] + bv;
            if (col < HID) C[(size_t)row * HID + col] = f2bf(v);
            s += v;
            q += v * v;
        }
        s += __shfl_down(s, 32, 64); s += __shfl_down(s, 16, 64);
        q += __shfl_down(q, 32, 64); q += __shfl_down(q, 16, 64);
        if (lane < 16) {
            atomicAdd(&scol[lc], s);
            atomicAdd(&qcol[lc], q);
        }
    }
    __syncthreads();
    if (tid < BNT) {
        int col = n0 + tid;
        if (col < HID) {
            atomicAdd(&sums[col], scol[tid]);
            atomicAdd(&sums[HID + col], qcol[tid]);
        }
    }
}

// ---------------- final: finalize3 (in-block, strided fill) + BN3+ReLU+rowsum --------------
__global__ __launch_bounds__(256) void final_kernel(const unsigned short* __restrict__ H3,
                                                    const float* __restrict__ sums,
                                                    const float* __restrict__ g,
                                                    const float* __restrict__ bt,
                                                    const float* __restrict__ f12,
                                                    const float* __restrict__ bias,
                                                    float* __restrict__ out) {
    __shared__ float ssc[HID], ssh[HID];
    int tid = threadIdx.x;
    const float invN = 1.f / (float)NROWS;
    for (int j = tid; j < HID; j += 256) {
        float mu = sums[j] * invN;
        float var = sums[HID + j] * invN - mu * mu;
        float rstd = rsqrtf(var + BN_EPS);
        float sc = g[j] * rstd;
        ssc[j] = sc;
        ssh[j] = bt[j] - mu * sc;
    }
    __syncthreads();
    int wave = tid >> 6, lane = tid & 63;
    int n = blockIdx.x * 4 + wave;
    float acc = 0.f;
    if (lane < 50) {
        short8v v = *(const short8v*)(H3 + (size_t)n * HID + lane * 8);
        #pragma unroll
        for (int e = 0; e < 8; ++e) {
            int k = lane * 8 + e;
            float x = bf2f((unsigned short)v[e]) * ssc[k] + ssh[k];
            acc += fmaxf(x, 0.f);
        }
    }
    #pragma unroll
    for (int o = 32; o; o >>= 1) acc += __shfl_down(acc, o, 64);
    if (lane == 0) out[n] = acc + f12[n] + bias[0];
}

// ---------------- launch ----------------
extern "C" void kernel_launch(void* const* d_in, const int* in_sizes, int n_in,
                              void* d_out, int out_size, void* d_ws, size_t ws_size,
                              hipStream_t stream) {
    const int* Xi = (const int*)d_in[0];
    const float* Xv = (const float*)d_in[1];
    const float* emb1 = (const float*)d_in[2];
    const float* emb2 = (const float*)d_in[3];
    const float* W1 = (const float*)d_in[4];
    const float* b1 = (const float*)d_in[5];
    const float* g1 = (const float*)d_in[6];
    const float* bt1 = (const float*)d_in[7];
    const float* W2 = (const float*)d_in[8];
    const float* b2 = (const float*)d_in[9];
    const float* g2 = (const float*)d_in[10];
    const float* bt2 = (const float*)d_in[11];
    const float* W3 = (const float*)d_in[12];
    const float* b3 = (const float*)d_in[13];
    const float* g3 = (const float*)d_in[14];
    const float* bt3 = (const float*)d_in[15];
    const float* bias = (const float*)d_in[16];

    char* ws = (char*)d_ws;
    size_t o_f12 = 0;
    size_t o_h0  = 65536;
    size_t o_h1  = o_h0 + (size_t)NROWS * K1T * 2;
    size_t o_w1  = o_h1 + (size_t)NROWS * HID * 2;
    size_t o_w2  = o_w1 + (size_t)448 * K1T * 2;
    size_t o_w3  = o_w2 + (size_t)448 * K2T * 2;
    size_t o_sums = o_w3 + (size_t)448 * K2T * 2;

    float* f12 = (float*)(ws + o_f12);
    unsigned short* h0 = (unsigned short*)(ws + o_h0);
    unsigned short* h1 = (unsigned short*)(ws + o_h1);
    unsigned short* h2 = (unsigned short*)(ws + o_h0);   // alias: h0 dead after gemm1
    unsigned short* h3 = (unsigned short*)(ws + o_h1);   // alias: h1 dead after gemm2
    unsigned short* w1b = (unsigned short*)(ws + o_w1);
    unsigned short* w2b = (unsigned short*)(ws + o_w2);
    unsigned short* w3b = (unsigned short*)(ws + o_w3);
    float* sums1 = (float*)(ws + o_sums);
    float* sums2 = sums1 + 800;
    float* sums3 = sums2 + 800;
    float* out = (float*)d_out;

    prep_kernel<<<EMB_BLOCKS + CVT_BLOCKS + 1, 256, 0, stream>>>(
        Xi, Xv, emb1, emb2, W1, W2, W3, h0, f12, w1b, w2b, w3b, sums1);

    dim3 ggrid(NROWS / BM, 2);   // 256 x 2 = 512 blocks -> 2 blocks/CU

    gemm_kernel<false><<<ggrid, 512, 0, stream>>>(h0, K1T, K1T, K1T, w1b, b1,
                                                  nullptr, nullptr, nullptr, h1, sums1);
    gemm_kernel<true><<<ggrid, 512, 0, stream>>>(h1, HID, HID, K2T, w2b, b2,
                                                 sums1, g1, bt1, h2, sums2);
    gemm_kernel<true><<<ggrid, 512, 0, stream>>>(h2, HID, HID, K2T, w3b, b3,
                                                 sums2, g2, bt2, h3, sums3);
    final_kernel<<<NROWS / 4, 256, 0, stream>>>(h3, sums3, g3, bt3, f12, bias, out);
}

// Round 9
// 416.481 us; speedup vs baseline: 1.0253x; 1.0253x over previous
//
#include <hip/hip_runtime.h>

// ---------------- constants ----------------
#define NROWS 16384
#define NF 39
#define NV 100000
#define NE 16
#define HID 400
#define K1 624     // real K of layer 1 (39*16)
#define K1T 640    // padded K span for layer 1 (h0 zero-padded to this)
#define K2T 448    // padded K span for layers 2/3 (real 400)
#define BN_EPS 1e-5f

typedef short short8v __attribute__((ext_vector_type(8)));
typedef short short4v __attribute__((ext_vector_type(4)));
typedef float float4v __attribute__((ext_vector_type(4)));

__device__ __forceinline__ float bf2f(unsigned short u) {
    unsigned int x = ((unsigned int)u) << 16;
    return __uint_as_float(x);
}
__device__ __forceinline__ unsigned short f2bf(float f) {
    unsigned int x = __float_as_uint(f);
    unsigned int r = (x + 0x7FFFu + ((x >> 16) & 1u)) >> 16;
    return (unsigned short)r;
}

// async global->LDS DMA, 16B per lane. LDS dest is wave-uniform base + lane*16.
__device__ __forceinline__ void gload16(const unsigned short* g, unsigned short* l) {
    __builtin_amdgcn_global_load_lds(
        (const __attribute__((address_space(1))) unsigned int*)g,
        (__attribute__((address_space(3))) unsigned int*)l,
        16, 0, 0);
}

// Counted-wait barriers (proven R4). Raw s_barrier does NOT auto-drain counters,
// so the 6 next-tile loads stay in flight across the MFMA phase.
__device__ __forceinline__ void bar_vm6() {
    asm volatile("s_waitcnt vmcnt(6) lgkmcnt(0)" ::: "memory");
    __builtin_amdgcn_s_barrier();
    __builtin_amdgcn_sched_barrier(0);
}
__device__ __forceinline__ void bar_vm0() {
    asm volatile("s_waitcnt vmcnt(0) lgkmcnt(0)" ::: "memory");
    __builtin_amdgcn_s_barrier();
    __builtin_amdgcn_sched_barrier(0);
}
__device__ __forceinline__ void bar_lgkm() {
    asm volatile("s_waitcnt lgkmcnt(0)" ::: "memory");
    __builtin_amdgcn_s_barrier();
    __builtin_amdgcn_sched_barrier(0);
}

// ---------------- prep: embed (blocks 0..1023) + weight-convert + zero sums -------------
// R9 embed: 16-lane-per-row structure (math HW-validated by R3's passing run).
// Each lane owns component quarter q=lg&3 (e = q*4+j), issues 10 independent emb2
// gathers + 3 emb1 gathers (13 VMEM in flight vs ~3 before), keeps everything in
// registers (no LDS, no barriers, no second gather pass), reduces per-e ss/sm with
// width-16 butterflies, writes h0 directly as short4v.
#define EMB_BLOCKS 1024           // 16 rows per 256-thread block
#define W1E (448 * 640)           // 286720
#define W2E (448 * 448)           // 200704
#define TCVT (W1E + 2 * W2E)      // 688128 elems
#define CVT_BLOCKS (TCVT / 8 / 256)   // 336

__global__ __launch_bounds__(256) void prep_kernel(const int* __restrict__ Xi,
                                                   const float* __restrict__ Xv,
                                                   const float* __restrict__ emb1,
                                                   const float* __restrict__ emb2,
                                                   const float* __restrict__ W1,
                                                   const float* __restrict__ W2,
                                                   const float* __restrict__ W3,
                                                   unsigned short* __restrict__ h0,
                                                   float* __restrict__ f12,
                                                   unsigned short* __restrict__ w1b,
                                                   unsigned short* __restrict__ w2b,
                                                   unsigned short* __restrict__ w3b,
                                                   float* __restrict__ sums) {
    int b = blockIdx.x;
    int tid = threadIdx.x;
    if (b < EMB_BLOCKS) {
        int g = tid >> 4;          // group 0..15: one row per 16-lane group
        int lg = tid & 15;
        int q = lg & 3;            // fixed component quarter: e = q*4 + j
        int a = lg >> 2;           // f-partition: lane handles f = a + 4t
        int n = b * 16 + g;
        const float4* e2 = (const float4*)emb2;

        // index/value loads (row's Xi/Xv lines are L1-hot after first lane touches)
        int idxA[10]; float xvA[10];
        #pragma unroll
        for (int t = 0; t < 10; ++t) {
            int i = lg + 16 * t;
            idxA[t] = 0; xvA[t] = 0.f;
            if (i < NF * 4) {
                int f = a + 4 * t;
                idxA[t] = Xi[(size_t)n * NF + f];
                xvA[t] = Xv[(size_t)n * NF + f];
            }
        }
        int idxB[3]; float xvB[3];
        #pragma unroll
        for (int t = 0; t < 3; ++t) {
            int f = lg + 16 * t;
            idxB[t] = 0; xvB[t] = 0.f;
            if (f < NF) {
                idxB[t] = Xi[(size_t)n * NF + f];
                xvB[t] = Xv[(size_t)n * NF + f];
            }
        }
        // 13 independent gathers in flight (10 emb2 16B + 3 emb1 4B)
        float4 vv[10];
        #pragma unroll
        for (int t = 0; t < 10; ++t) {
            int i = lg + 16 * t;
            if (i < NF * 4) {
                int f = a + 4 * t;
                vv[t] = e2[((size_t)f * NV + (size_t)idxA[t]) * 4 + q];
            }
        }
        float f1 = 0.f;
        #pragma unroll
        for (int t = 0; t < 3; ++t) {
            int f = lg + 16 * t;
            if (f < NF)
                f1 += emb1[(size_t)f * NV + (size_t)idxB[t]] * xvB[t];
        }
        // per-e ss/sm accumulation (e = q*4 + j, j=0..3)
        float ssA[4] = {0.f, 0.f, 0.f, 0.f};
        float smA[4] = {0.f, 0.f, 0.f, 0.f};
        #pragma unroll
        for (int t = 0; t < 10; ++t) {
            int i = lg + 16 * t;
            if (i < NF * 4) {
                float m = xvA[t];
                float p0 = vv[t].x * m, p1 = vv[t].y * m;
                float p2 = vv[t].z * m, p3 = vv[t].w * m;
                ssA[0] += p0 * p0; ssA[1] += p1 * p1;
                ssA[2] += p2 * p2; ssA[3] += p3 * p3;
                smA[0] += p0; smA[1] += p1; smA[2] += p2; smA[3] += p3;
            }
        }
        // reduce over f-partition lanes (bits 2,3 of lg)
        #pragma unroll
        for (int j = 0; j < 4; ++j) {
            ssA[j] += __shfl_xor(ssA[j], 4, 16);
            ssA[j] += __shfl_xor(ssA[j], 8, 16);
            smA[j] += __shfl_xor(smA[j], 4, 16);
            smA[j] += __shfl_xor(smA[j], 8, 16);
        }
        float rn4[4];
        float f2p = 0.f;
        #pragma unroll
        for (int j = 0; j < 4; ++j) {
            rn4[j] = 1.f / fmaxf(sqrtf(ssA[j]), 1e-12f);
            float s1 = smA[j] * rn4[j];
            f2p += 0.5f * (s1 * s1 - ssA[j] * rn4[j] * rn4[j]);
        }
        // f2 across q-groups (uniform within each q-group after xor4/8)
        f2p += __shfl_xor(f2p, 1, 16);
        f2p += __shfl_xor(f2p, 2, 16);
        #pragma unroll
        for (int o = 1; o < 16; o <<= 1) f1 += __shfl_xor(f1, o, 16);
        if (lg == 0) f12[n] = f1 + f2p;
        // h0 store: unit i covers elems 4i..4i+3; i in [156,160) -> zero pad (624..639)
        #pragma unroll
        for (int t = 0; t < 10; ++t) {
            int i = lg + 16 * t;
            short4v pk = (short4v){0, 0, 0, 0};
            if (i < NF * 4) {
                float m = xvA[t];
                pk[0] = (short)f2bf((vv[t].x * m) * rn4[0]);
                pk[1] = (short)f2bf((vv[t].y * m) * rn4[1]);
                pk[2] = (short)f2bf((vv[t].z * m) * rn4[2]);
                pk[3] = (short)f2bf((vv[t].w * m) * rn4[3]);
            }
            *(short4v*)(h0 + (size_t)n * K1T + (size_t)i * 4) = pk;
        }
        return;
    }
    b -= EMB_BLOCKS;
    if (b < CVT_BLOCKS) {
        int gidx = b * 256 + tid;
        int e = gidx * 8;
        if (e < TCVT) {
            const float* W; unsigned short* O; int Kreal, Kt, base;
            if (e < W1E) { W = W1; O = w1b; Kreal = K1; Kt = K1T; base = 0; }
            else if (e < W1E + W2E) { W = W2; O = w2b; Kreal = HID; Kt = K2T; base = W1E; }
            else { W = W3; O = w3b; Kreal = HID; Kt = K2T; base = W1E + W2E; }
            int le = e - base;
            int r = le / Kt, k = le % Kt;
            short8v o;
            #pragma unroll
            for (int ee = 0; ee < 8; ++ee) {
                int kk = k + ee;
                o[ee] = (r < HID && kk < Kreal) ? (short)f2bf(W[(size_t)r * Kreal + kk]) : (short)0;
            }
            *(short8v*)(O + (size_t)r * Kt + k) = o;
        }
        return;
    }
    for (int i = tid; i < 2400; i += 256) sums[i] = 0.f;
}

// ---------------- bf16 MFMA GEMM: 512 thr, BM=128, BNT=224 (R4, passing) --------------
// Counted-vmcnt pipeline. Per K-step every wave issues EXACTLY 6 VMEM ops
// (A: 2 DMA or 2 reg-loads; B: 4 DMA equalized). Barrier #1 waits vmcnt(6): drains
// the PREVIOUS step's 6, leaves this step's 6 in flight under the MFMA phase.
#define BM 128
#define BNT 224
#define BK 64

template <bool FUSE_BN>
__global__ __launch_bounds__(512, 2) void gemm_kernel(const unsigned short* __restrict__ A,
                                                      int lda, int Kreal, int Kt,
                                                      const unsigned short* __restrict__ W,  // 448 x Kt
                                                      const float* __restrict__ bias,
                                                      const float* __restrict__ psums,
                                                      const float* __restrict__ g,
                                                      const float* __restrict__ bt,
                                                      unsigned short* __restrict__ C,        // ldc = 400
                                                      float* __restrict__ sums) {
    __shared__ __align__(16) unsigned short As[2][BM * BK];    // 2 x 16 KB
    __shared__ __align__(16) unsigned short Bs[2][BNT * BK];   // 2 x 28 KB
    __shared__ float ssc[K2T], ssh[K2T];
    __shared__ float scol[BNT], qcol[BNT];
    int tid = threadIdx.x;
    int wave = tid >> 6, lane = tid & 63;
    int quad = lane >> 4, l16 = lane & 15;
    int mi = wave & 3, nj = wave >> 2;
    int m0 = blockIdx.x * BM;
    int n0 = blockIdx.y * BNT;
    int wbase = tid & ~63;   // wave*64

    if (FUSE_BN && tid < K2T) {
        float sc = 0.f, sh = 0.f;
        if (tid < HID) {
            const float invN = 1.f / (float)NROWS;
            float mu = psums[tid] * invN;
            float var = psums[HID + tid] * invN - mu * mu;
            float rstd = rsqrtf(var + BN_EPS);
            sc = g[tid] * rstd;
            sh = bt[tid] - mu * sc;
        }
        ssc[tid] = sc; ssh[tid] = sh;
    }
    if (tid < BNT) { scol[tid] = 0.f; qcol[tid] = 0.f; }

    const short8v zero8 = (short8v){0, 0, 0, 0, 0, 0, 0, 0};
    short8v Ar[2];

    auto stageA_g = [&](int buf, int kt) {
        #pragma unroll
        for (int i = 0; i < 2; ++i) {
            int v = tid + i * 512;
            int r = v >> 3, c = v & 7;
            int sc = c ^ (r & 7);
            gload16(A + (size_t)(m0 + r) * lda + kt + sc * 8,
                    &As[buf][(size_t)(i * 512 + wbase) * 8]);
        }
    };
    auto stageB = [&](int buf, int kt) {
        #pragma unroll
        for (int i2 = 0; i2 < 4; ++i2) {
            int v = tid + i2 * 512;
            int vv = (v < BNT * 8) ? v : tid;
            int dst = (v < BNT * 8) ? (i2 * 512 + wbase) : wbase;
            int r = vv >> 3, c = vv & 7;
            int sc = c ^ (r & 7);
            gload16(W + (size_t)(n0 + r) * Kt + kt + sc * 8,
                    &Bs[buf][(size_t)dst * 8]);
        }
    };
    auto loadA_regs = [&](int kt) {
        #pragma unroll
        for (int i = 0; i < 2; ++i) {
            int v = tid + i * 512;
            int r = v >> 3, gc = v & 7;
            int k = kt + gc * 8;
            Ar[i] = (k < Kreal) ? *(const short8v*)(A + (size_t)(m0 + r) * lda + k) : zero8;
        }
    };
    auto writeA_lds = [&](int buf, int kt) {
        #pragma unroll
        for (int i = 0; i < 2; ++i) {
            int v = tid + i * 512;
            int r = v >> 3, gc = v & 7;
            short8v val = Ar[i];
            #pragma unroll
            for (int e = 0; e < 8; ++e) {
                int k = kt + gc * 8 + e;
                float x = bf2f((unsigned short)val[e]);
                val[e] = (short)f2bf(fmaxf(x * ssc[k] + ssh[k], 0.f));
            }
            *(short8v*)(&As[buf][r * BK + ((gc ^ (r & 7)) * 8)]) = val;
        }
    };

    float4v acc[2][7];
    #pragma unroll
    for (int i = 0; i < 2; ++i)
        #pragma unroll
        for (int f = 0; f < 7; ++f)
            acc[i][f] = (float4v){0.f, 0.f, 0.f, 0.f};

    // prologue: stage tile 0, full drain (once)
    if (FUSE_BN) loadA_regs(0); else stageA_g(0, 0);
    stageB(0, 0);
    __syncthreads();                       // ssc/ssh + scol ready; tile-0 DMA drained
    if (FUSE_BN) { writeA_lds(0, 0); __syncthreads(); }

    int nsteps = Kt / BK;
    int buf = 0;
    for (int s = 0; s < nsteps; ++s) {
        bool more = (s + 1 < nsteps);
        if (more) {
            if (FUSE_BN) loadA_regs((s + 1) * BK); else stageA_g(buf ^ 1, (s + 1) * BK);
            stageB(buf ^ 1, (s + 1) * BK);
        }
        if (more) bar_vm6(); else bar_vm0();   // barrier #1: buf staged & published
        __builtin_amdgcn_s_setprio(1);
        #pragma unroll
        for (int kk = 0; kk < BK; kk += 32) {
            int kc = kk >> 3;              // 0 or 4
            short8v af[2], bfr[7];
            #pragma unroll
            for (int i = 0; i < 2; ++i) {
                int r = mi * 32 + i * 16 + l16;
                af[i] = *(const short8v*)(&As[buf][r * BK + (((quad + kc) ^ (r & 7)) * 8)]);
            }
            #pragma unroll
            for (int f = 0; f < 7; ++f) {
                int r = nj * 112 + f * 16 + l16;
                bfr[f] = *(const short8v*)(&Bs[buf][r * BK + (((quad + kc) ^ (r & 7)) * 8)]);
            }
            #pragma unroll
            for (int i = 0; i < 2; ++i)
                #pragma unroll
                for (int f = 0; f < 7; ++f)
                    acc[i][f] = __builtin_amdgcn_mfma_f32_16x16x32_bf16(af[i], bfr[f], acc[i][f], 0, 0, 0);
        }
        __builtin_amdgcn_s_setprio(0);
        if (FUSE_BN && more) writeA_lds(buf ^ 1, (s + 1) * BK);  // hid under next wait
        bar_lgkm();                        // barrier #2: readers of buf done; ds_writes out
        buf ^= 1;
    }

    // epilogue: store C + per-column stats. C/D layout: col=lane&15, row=quad*4+reg
    #pragma unroll
    for (int f = 0; f < 7; ++f) {
        int lc = nj * 112 + f * 16 + l16;
        int col = n0 + lc;
        float bv = (col < HID) ? bias[col] : 0.f;
        float s = 0.f, q = 0.f;
        #pragma unroll
        for (int i = 0; i < 2; ++i) {
            #pragma unroll
            for (int r = 0; r < 4; ++r) {
                int row = m0 + mi * 32 + i * 16 + quad * 4 + r;
                float v = acc[i][f][r] + bv;
                if (col < HID) C[(size_t)row * HID + col] = f2bf(v);
                s += v;
                q += v * v;
            }
        }
        s += __shfl_down(s, 32, 64); s += __shfl_down(s, 16, 64);
        q += __shfl_down(q, 32, 64); q += __shfl_down(q, 16, 64);
        if (lane < 16) {
            atomicAdd(&scol[lc], s);
            atomicAdd(&qcol[lc], q);
        }
    }
    __syncthreads();
    if (tid < BNT) {
        int col = n0 + tid;
        if (col < HID) {
            atomicAdd(&sums[col], scol[tid]);
            atomicAdd(&sums[HID + col], qcol[tid]);
        }
    }
}

// ---------------- final: finalize3 (in-block, strided fill) + BN3+ReLU+rowsum --------------
__global__ __launch_bounds__(256) void final_kernel(const unsigned short* __restrict__ H3,
                                                    const float* __restrict__ sums,
                                                    const float* __restrict__ g,
                                                    const float* __restrict__ bt,
                                                    const float* __restrict__ f12,
                                                    const float* __restrict__ bias,
                                                    float* __restrict__ out) {
    __shared__ float ssc[HID], ssh[HID];
    int tid = threadIdx.x;
    const float invN = 1.f / (float)NROWS;
    for (int j = tid; j < HID; j += 256) {
        float mu = sums[j] * invN;
        float var = sums[HID + j] * invN - mu * mu;
        float rstd = rsqrtf(var + BN_EPS);
        float sc = g[j] * rstd;
        ssc[j] = sc;
        ssh[j] = bt[j] - mu * sc;
    }
    __syncthreads();
    int wave = tid >> 6, lane = tid & 63;
    int n = blockIdx.x * 4 + wave;
    float acc = 0.f;
    if (lane < 50) {
        short8v v = *(const short8v*)(H3 + (size_t)n * HID + lane * 8);
        #pragma unroll
        for (int e = 0; e < 8; ++e) {
            int k = lane * 8 + e;
            float x = bf2f((unsigned short)v[e]) * ssc[k] + ssh[k];
            acc += fmaxf(x, 0.f);
        }
    }
    #pragma unroll
    for (int o = 32; o; o >>= 1) acc += __shfl_down(acc, o, 64);
    if (lane == 0) out[n] = acc + f12[n] + bias[0];
}

// ---------------- launch ----------------
extern "C" void kernel_launch(void* const* d_in, const int* in_sizes, int n_in,
                              void* d_out, int out_size, void* d_ws, size_t ws_size,
                              hipStream_t stream) {
    const int* Xi = (const int*)d_in[0];
    const float* Xv = (const float*)d_in[1];
    const float* emb1 = (const float*)d_in[2];
    const float* emb2 = (const float*)d_in[3];
    const float* W1 = (const float*)d_in[4];
    const float* b1 = (const float*)d_in[5];
    const float* g1 = (const float*)d_in[6];
    const float* bt1 = (const float*)d_in[7];
    const float* W2 = (const float*)d_in[8];
    const float* b2 = (const float*)d_in[9];
    const float* g2 = (const float*)d_in[10];
    const float* bt2 = (const float*)d_in[11];
    const float* W3 = (const float*)d_in[12];
    const float* b3 = (const float*)d_in[13];
    const float* g3 = (const float*)d_in[14];
    const float* bt3 = (const float*)d_in[15];
    const float* bias = (const float*)d_in[16];

    char* ws = (char*)d_ws;
    size_t o_f12 = 0;
    size_t o_h0  = 65536;
    size_t o_h1  = o_h0 + (size_t)NROWS * K1T * 2;
    size_t o_w1  = o_h1 + (size_t)NROWS * HID * 2;
    size_t o_w2  = o_w1 + (size_t)448 * K1T * 2;
    size_t o_w3  = o_w2 + (size_t)448 * K2T * 2;
    size_t o_sums = o_w3 + (size_t)448 * K2T * 2;

    float* f12 = (float*)(ws + o_f12);
    unsigned short* h0 = (unsigned short*)(ws + o_h0);
    unsigned short* h1 = (unsigned short*)(ws + o_h1);
    unsigned short* h2 = (unsigned short*)(ws + o_h0);   // alias: h0 dead after gemm1 (split kernels: safe)
    unsigned short* h3 = (unsigned short*)(ws + o_h1);   // alias: h1 dead after gemm2
    unsigned short* w1b = (unsigned short*)(ws + o_w1);
    unsigned short* w2b = (unsigned short*)(ws + o_w2);
    unsigned short* w3b = (unsigned short*)(ws + o_w3);
    float* sums1 = (float*)(ws + o_sums);
    float* sums2 = sums1 + 800;
    float* sums3 = sums2 + 800;
    float* out = (float*)d_out;

    prep_kernel<<<EMB_BLOCKS + CVT_BLOCKS + 1, 256, 0, stream>>>(
        Xi, Xv, emb1, emb2, W1, W2, W3, h0, f12, w1b, w2b, w3b, sums1);

    dim3 ggrid(NROWS / BM, 2);

    gemm_kernel<false><<<ggrid, 512, 0, stream>>>(h0, K1T, K1T, K1T, w1b, b1,
                                                  nullptr, nullptr, nullptr, h1, sums1);
    gemm_kernel<true><<<ggrid, 512, 0, stream>>>(h1, HID, HID, K2T, w2b, b2,
                                                 sums1, g1, bt1, h2, sums2);
    gemm_kernel<true><<<ggrid, 512, 0, stream>>>(h2, HID, HID, K2T, w3b, b3,
                                                 sums2, g2, bt2, h3, sums3);
    final_kernel<<<NROWS / 4, 256, 0, stream>>>(h3, sums3, g3, bt3, f12, bias, out);
}